// Round 7
// baseline (207.966 us; speedup 1.0000x reference)
//
#include <hip/hip_runtime.h>
#include <hip/hip_bf16.h>
#include <cstddef>
#include <cstdint>

// (B,T,I,H,K) = (32,1024,512,512,2)
#define B_  32
#define T_  1024
#define I_  512
#define H_  512
#define M_  (B_ * T_)     // 32768
#define TP_ 1025          // padded T rows (row 0 = zeros) per batch

typedef __bf16 bf16x8  __attribute__((ext_vector_type(8)));
typedef float  floatx4 __attribute__((ext_vector_type(4)));
typedef unsigned short ushort8v __attribute__((ext_vector_type(8)));
typedef unsigned long long u64;

__device__ __forceinline__ unsigned short f2bf(float f) {
    uint32_t u = __float_as_uint(f);
    return (unsigned short)((u + 0x7FFFu + ((u >> 16) & 1u)) >> 16);
}
__device__ __forceinline__ float sigm(float x) {
    return __builtin_amdgcn_rcpf(1.f + __expf(-x));
}

#define GLL(src, dst) __builtin_amdgcn_global_load_lds( \
    (const __attribute__((address_space(1))) void*)(src), \
    (__attribute__((address_space(3))) void*)(dst), 16, 0, 0)

// ---------------------------------------------------------------------------
// Prep.
//  Part 1: Ab2[b][trow][i] bf16 (trow 0 = zeros, else x[b][trow-1]).
//  Part 2: fragment-ordered weight pack
//    Wq[gate(2)][ni(4)][ksub(32)][wn(2)][c(4)][lane(64)][8] bf16:
//    n_col = ni*128 + wn*64 + c*16 + (lane&15);
//    k     = ksub*32 + (lane>>4)*8 + j;  tap = k>>9; i = k&511.
//    One frag = 64 lanes x 16 B contiguous -> coalesced dwordx4 per wave.
//  Part 3: zero Hpub (1 MB) + counter (ws is re-poisoned 0xAA each launch).
// ---------------------------------------------------------------------------
#define NB_BUILD 8200    // 32*1025*512 / 8 / 256
#define NB_PACK  512     // 1,048,576 elems / 8 / 256
#define NB_ZERO  256     // 1 MB / 16 B / 256

__global__ __launch_bounds__(256) void prep(const float* __restrict__ x,
                                            const float* __restrict__ Wf,
                                            const float* __restrict__ Wz,
                                            unsigned short* __restrict__ Ab2,
                                            unsigned short* __restrict__ Wq,
                                            uint4* __restrict__ HpubZ,
                                            uint32_t* __restrict__ cnt) {
    if (blockIdx.x < NB_BUILD) {
        int g = blockIdx.x * 256 + threadIdx.x;     // 2,099,200
        int idx8 = g << 3;
        int row = idx8 >> 9;                        // 0 .. 32*1025-1
        int col = idx8 & 511;
        int b    = (int)((unsigned)row / TP_);
        int trow = row - b * TP_;
        ushort8v o = {0, 0, 0, 0, 0, 0, 0, 0};
        if (trow > 0) {
            const float* src = &x[((size_t)b * T_ + (trow - 1)) * I_ + col];
            float4 v0 = *(const float4*)src;
            float4 v1 = *(const float4*)(src + 4);
            o[0] = f2bf(v0.x); o[1] = f2bf(v0.y); o[2] = f2bf(v0.z); o[3] = f2bf(v0.w);
            o[4] = f2bf(v1.x); o[5] = f2bf(v1.y); o[6] = f2bf(v1.z); o[7] = f2bf(v1.w);
        }
        *(ushort8v*)&Ab2[(size_t)idx8] = o;
    } else if (blockIdx.x < NB_BUILD + NB_PACK) {
        int cid = (blockIdx.x - NB_BUILD) * 256 + threadIdx.x;  // 0..131071
        int lane = cid & 63;
        int c    = (cid >> 6) & 3;
        int wn   = (cid >> 8) & 1;
        int ksub = (cid >> 9) & 31;
        int ni   = (cid >> 14) & 3;
        int gate = (cid >> 16) & 1;
        int n_col = ni * 128 + wn * 64 + c * 16 + (lane & 15);
        const float* G = gate ? Wz : Wf;
        ushort8v o;
        #pragma unroll
        for (int j = 0; j < 8; ++j) {
            int k   = ksub * 32 + (lane >> 4) * 8 + j;
            int tap = k >> 9;
            int i   = k & 511;
            o[j] = f2bf(G[n_col * (I_ * 2) + i * 2 + tap]);
        }
        *(ushort8v*)&Wq[(size_t)cid * 8] = o;
    } else {
        int g = (blockIdx.x - NB_BUILD - NB_PACK) * 256 + threadIdx.x; // 0..65535
        HpubZ[g] = make_uint4(0, 0, 0, 0);
        if (g == 0) *cnt = 0;
    }
}

// ---------------------------------------------------------------------------
// Fused dual-gate MFMA GEMM + full scan via decoupled lookback.
// vid = atomicAdd start order; pos = vid>>7 (t-chunk of 128), chain = vid&127
// = (ni,b). Pred (lower vid) started earlier -> resident or done -> no
// deadlock. Handoff: relaxed u64 atomics only (no fences; round-5 lesson).
// K-loop: A staged in LDS via global_load_lds (XOR-swizzled); B fragments
// loaded DIRECTLY global->VGPR from the fragment-ordered Wq pack (L2-hot,
// coalesced) -> LDS reads/pair cut 3x, barrier drain covers only 4 GLLs.
// ---------------------------------------------------------------------------
__global__ __launch_bounds__(256, 2) void mfma_gemm_scan(
        const unsigned short* __restrict__ Ab2,  // [32][1025][512]
        const unsigned short* __restrict__ Wq,   // fragment-ordered, 2 MB
        const float* __restrict__ biasF,
        const float* __restrict__ biasZ,
        float* __restrict__ out,                 // [M_][512] fp32
        u64* __restrict__ Hpub,                  // [8][128][128]
        uint32_t* __restrict__ counter) {
    // K-loop: A substage s at smem + s*4096 shorts (8 KB each).
    // Epilogue reuse: seg = float2[32][128] at [0,32KB); hinL at [32KB,48KB)
    __shared__ unsigned short smem[24576];       // 48 KB
    __shared__ uint32_t vid_s;

    const int tid = threadIdx.x;
    if (tid == 0) vid_s = atomicAdd(counter, 1u);
    __syncthreads();
    const int vid   = (int)vid_s;
    const int pos   = vid >> 7;                  // 0..7  t-chunk
    const int chain = vid & 127;                 // (ni,b)
    const int b     = chain & 31;
    const int ni    = chain >> 5;
    const int h0    = ni * 128;
    const int browBase = b * TP_ + pos * 128;    // Ab2 row of tile t=0, tap0

    const int lane = tid & 63;
    const int wave = tid >> 6;
    const int wm   = wave >> 1, wn = wave & 1;
    const int lm   = lane & 15, quad = lane >> 4;

    // A staging chunk ids (512 chunks/substage; wave covers 128: lane, lane+64)
    const int c0 = wave * 128 + lane;
    const int c1 = c0 + 64;
    const int r0 = c0 >> 2, q0 = (c0 & 3) ^ ((r0 >> 2) & 3);
    const int r1 = c1 >> 2, q1 = (c1 & 3) ^ ((r1 >> 2) & 3);

    const unsigned short* pA0 = Ab2 + (size_t)(browBase + r0) * 512 + q0 * 8;
    const unsigned short* pA1 = Ab2 + (size_t)(browBase + r1) * 512 + q1 * 8;

    unsigned short* dA0 = smem + wave * 1024;    // + s*4096
    unsigned short* dA1 = smem + wave * 1024 + 512;

    // B fragment base: frag(gate,ksub,c) = wq + gate*524288 + ksub*4096 + c*512
    const unsigned short* wq = Wq + ni * 131072 + wn * 2048 + lane * 8;

    int offA[4];
    #pragma unroll
    for (int r = 0; r < 4; ++r) {
        int ml = wm * 64 + r * 16 + lm;
        offA[r] = (4 * ml + (quad ^ ((ml >> 2) & 3))) * 8;
    }

    floatx4 accF[4][4] = {};
    floatx4 accZ[4][4] = {};

    for (int kt2 = 0; kt2 < 16; ++kt2) {
        const int tap = kt2 >> 3;
        const int i0  = (kt2 & 7) * 64;
        #pragma unroll
        for (int s = 0; s < 2; ++s) {
            const int aoff = tap * 512 + i0 + s * 32;
            GLL(pA0 + aoff, dA0 + s * 4096);
            GLL(pA1 + aoff, dA1 + s * 4096);
        }
        __syncthreads();

        #pragma unroll
        for (int s = 0; s < 2; ++s) {
            const int ksub = kt2 * 2 + s;
            const unsigned short* wqk = wq + ksub * 4096;
            bf16x8 af[4], bF[4], bZ[4];
            #pragma unroll
            for (int c = 0; c < 4; ++c) {
                bF[c] = *(const bf16x8*)(wqk + c * 512);
                bZ[c] = *(const bf16x8*)(wqk + 524288 + c * 512);
            }
            #pragma unroll
            for (int r = 0; r < 4; ++r) af[r] = *(const bf16x8*)(smem + s * 4096 + offA[r]);
            #pragma unroll
            for (int r = 0; r < 4; ++r) {
                #pragma unroll
                for (int c = 0; c < 4; ++c) {
                    accF[r][c] = __builtin_amdgcn_mfma_f32_16x16x32_bf16(
                                    af[r], bF[c], accF[r][c], 0, 0, 0);
                    accZ[r][c] = __builtin_amdgcn_mfma_f32_16x16x32_bf16(
                                    af[r], bZ[c], accZ[r][c], 0, 0, 0);
                }
            }
        }
        __syncthreads();
    }

    // ================= epilogue: sigmoid + segment affines =================
    float bfv[4], bzv[4];
    #pragma unroll
    for (int c = 0; c < 4; ++c) {
        int hc = h0 + wn * 64 + c * 16 + lm;
        bfv[c] = biasF[hc];
        bzv[c] = biasZ[hc];
    }

    float2* seg  = (float2*)smem;                // [32][128] 32 KB
    float*  hinL = (float*)&smem[16384];         // [32][128] 16 KB

    #pragma unroll
    for (int r = 0; r < 4; ++r) {
        const int sid = wm * 16 + r * 4 + quad;  // segment of 4 t's
        #pragma unroll
        for (int c = 0; c < 4; ++c) {
            float A = 1.f, C = 0.f;
            #pragma unroll
            for (int v = 0; v < 4; ++v) {
                float f = sigm(accF[r][c][v] + bfv[c]);
                float z = sigm(accZ[r][c][v] + bzv[c]);
                accF[r][c][v] = f;               // keep f
                accZ[r][c][v] = z;               // keep z
                A *= f;
                C = fmaf(f, C - z, z);
            }
            seg[sid * 128 + wn * 64 + c * 16 + lm] = make_float2(A, C);
        }
    }
    __syncthreads();

    // per-h block affine (threads 0..127), lookback, publish, local states
    float Hin = 0.f;
    if (tid < 128) {
        float At = 1.f, Ct = 0.f;
        #pragma unroll 8
        for (int s = 0; s < 32; ++s) {
            float2 sc = seg[s * 128 + tid];
            Ct = fmaf(sc.x, Ct, sc.y);
            At *= sc.x;
        }
        if (pos > 0) {
            u64* p = &Hpub[((size_t)(pos - 1) * 128 + chain) * 128 + tid];
            u64 v;
            while (((v = atomicAdd(p, 0ull)) >> 32) == 0ull)
                __builtin_amdgcn_s_sleep(2);
            Hin = __uint_as_float((uint32_t)v);
        }
        if (pos < 7) {
            float Hout = fmaf(At, Hin, Ct);
            u64 pv = 0x100000000ull | (u64)__float_as_uint(Hout);
            atomicExch(&Hpub[((size_t)pos * 128 + chain) * 128 + tid], pv);
        }
        // per-segment entry states
        float run = Hin;
        #pragma unroll 8
        for (int s = 0; s < 32; ++s) {
            hinL[s * 128 + tid] = run;
            float2 sc = seg[s * 128 + tid];
            run = fmaf(sc.x, run, sc.y);
        }
    }
    __syncthreads();

    // replay tile from registers, write output
    const int rowBase = b * T_ + pos * 128;
    #pragma unroll
    for (int r = 0; r < 4; ++r) {
        const int sid = wm * 16 + r * 4 + quad;
        #pragma unroll
        for (int c = 0; c < 4; ++c) {
            const int hc = h0 + wn * 64 + c * 16 + lm;
            float hs = hinL[sid * 128 + (hc - h0)];
            #pragma unroll
            for (int v = 0; v < 4; ++v) {
                float f = accF[r][c][v];
                float z = accZ[r][c][v];
                hs = fmaf(f, hs - z, z);
                const size_t row = (size_t)(rowBase + wm * 64 + r * 16 + quad * 4 + v);
                out[row * H_ + hc] = hs;
            }
        }
    }
}

// ---------------------------------------------------------------------------
extern "C" void kernel_launch(void* const* d_in, const int* in_sizes, int n_in,
                              void* d_out, int out_size, void* d_ws, size_t ws_size,
                              hipStream_t stream) {
    const float* x  = (const float*)d_in[0];
    const float* Wz = (const float*)d_in[2];
    const float* bz = (const float*)d_in[3];
    const float* Wf = (const float*)d_in[4];
    const float* bf = (const float*)d_in[5];
    float* out = (float*)d_out;

    char* ws = (char*)d_ws;
    unsigned short* Ab2  = (unsigned short*)(ws);                            // 33.6 MB
    unsigned short* Wq   = (unsigned short*)(ws + (size_t)34 * 1024 * 1024); // 2 MB
    u64*            Hpub = (u64*)(ws + (size_t)36 * 1024 * 1024);            // 1 MB
    uint32_t*       cnt  = (uint32_t*)(ws + (size_t)37 * 1024 * 1024);

    prep<<<NB_BUILD + NB_PACK + NB_ZERO, 256, 0, stream>>>(
        x, Wf, Wz, Ab2, Wq, (uint4*)Hpub, cnt);

    mfma_gemm_scan<<<1024, 256, 0, stream>>>(Ab2, Wq, bf, bz, out, Hpub, cnt);
}

// Round 8
// 202.132 us; speedup vs baseline: 1.0289x; 1.0289x over previous
//
#include <hip/hip_runtime.h>
#include <hip/hip_bf16.h>
#include <cstddef>
#include <cstdint>

// (B,T,I,H,K) = (32,1024,512,512,2)
#define B_  32
#define T_  1024
#define I_  512
#define H_  512
#define M_  (B_ * T_)     // 32768
#define TP_ 1025          // padded T rows (row 0 = zeros) per batch

typedef __bf16 bf16x8  __attribute__((ext_vector_type(8)));
typedef float  floatx4 __attribute__((ext_vector_type(4)));
typedef unsigned short ushort8v __attribute__((ext_vector_type(8)));
typedef unsigned long long u64;

__device__ __forceinline__ unsigned short f2bf(float f) {
    uint32_t u = __float_as_uint(f);
    return (unsigned short)((u + 0x7FFFu + ((u >> 16) & 1u)) >> 16);
}
__device__ __forceinline__ float sigm(float x) {
    return __builtin_amdgcn_rcpf(1.f + __expf(-x));
}

#define GLL(src, dst) __builtin_amdgcn_global_load_lds( \
    (const __attribute__((address_space(1))) void*)(src), \
    (__attribute__((address_space(3))) void*)(dst), 16, 0, 0)

// ---------------------------------------------------------------------------
// Prep.
//  Part 1: Ab2[b][trow][i] bf16 (trow 0 = zeros, else x[b][trow-1]).
//  Part 2: fragment-ordered weight pack
//    Wq[gate(2)][ni(4)][ksub(32)][wn(2)][c(4)][lane(64)][8] bf16.
//  Part 3: zero Hpub (1 MB) + counter (ws is re-poisoned 0xAA each launch).
// ---------------------------------------------------------------------------
#define NB_BUILD 8200    // 32*1025*512 / 8 / 256
#define NB_PACK  512     // 1,048,576 elems / 8 / 256
#define NB_ZERO  256     // 1 MB / 16 B / 256

__global__ __launch_bounds__(256) void prep(const float* __restrict__ x,
                                            const float* __restrict__ Wf,
                                            const float* __restrict__ Wz,
                                            unsigned short* __restrict__ Ab2,
                                            unsigned short* __restrict__ Wq,
                                            uint4* __restrict__ HpubZ,
                                            uint32_t* __restrict__ cnt) {
    if (blockIdx.x < NB_BUILD) {
        int g = blockIdx.x * 256 + threadIdx.x;     // 2,099,200
        int idx8 = g << 3;
        int row = idx8 >> 9;                        // 0 .. 32*1025-1
        int col = idx8 & 511;
        int b    = (int)((unsigned)row / TP_);
        int trow = row - b * TP_;
        ushort8v o = {0, 0, 0, 0, 0, 0, 0, 0};
        if (trow > 0) {
            const float* src = &x[((size_t)b * T_ + (trow - 1)) * I_ + col];
            float4 v0 = *(const float4*)src;
            float4 v1 = *(const float4*)(src + 4);
            o[0] = f2bf(v0.x); o[1] = f2bf(v0.y); o[2] = f2bf(v0.z); o[3] = f2bf(v0.w);
            o[4] = f2bf(v1.x); o[5] = f2bf(v1.y); o[6] = f2bf(v1.z); o[7] = f2bf(v1.w);
        }
        *(ushort8v*)&Ab2[(size_t)idx8] = o;
    } else if (blockIdx.x < NB_BUILD + NB_PACK) {
        int cid = (blockIdx.x - NB_BUILD) * 256 + threadIdx.x;  // 0..131071
        int lane = cid & 63;
        int c    = (cid >> 6) & 3;
        int wn   = (cid >> 8) & 1;
        int ksub = (cid >> 9) & 31;
        int ni   = (cid >> 14) & 3;
        int gate = (cid >> 16) & 1;
        int n_col = ni * 128 + wn * 64 + c * 16 + (lane & 15);
        const float* G = gate ? Wz : Wf;
        ushort8v o;
        #pragma unroll
        for (int j = 0; j < 8; ++j) {
            int k   = ksub * 32 + (lane >> 4) * 8 + j;
            int tap = k >> 9;
            int i   = k & 511;
            o[j] = f2bf(G[n_col * (I_ * 2) + i * 2 + tap]);
        }
        *(ushort8v*)&Wq[(size_t)cid * 8] = o;
    } else {
        int g = (blockIdx.x - NB_BUILD - NB_PACK) * 256 + threadIdx.x; // 0..65535
        HpubZ[g] = make_uint4(0, 0, 0, 0);
        if (g == 0) *cnt = 0;
    }
}

// ---------------------------------------------------------------------------
// Fused dual-gate MFMA GEMM + full scan via decoupled lookback.
// vid = atomicAdd start order. XCD-affine decode: the 4 ni-sharers of one
// (pos,b) A-tile get vids {v, v+8, v+16, v+24} -> same XCD (round-robin
// dispatch) -> A-tile fetched once into that XCD's L2 (round-7 lesson:
// scattered sharers caused 4x refetch, FETCH 130 MB, latency-bound K-loop).
//   low3 = vid&7; ni=(vid>>3)&3; rem=vid>>5; pos=rem>>2; b=((rem&3)<<3)|low3.
// Chain pred (pos-1) has vid-128 -> started earlier -> deadlock-free.
// Handoff: relaxed u64 atomics only (no fences; round-5 lesson).
// B fragments direct global->VGPR from fragment-ordered Wq (L2-hot).
// ---------------------------------------------------------------------------
__global__ __launch_bounds__(256, 2) void mfma_gemm_scan(
        const unsigned short* __restrict__ Ab2,  // [32][1025][512]
        const unsigned short* __restrict__ Wq,   // fragment-ordered, 2 MB
        const float* __restrict__ biasF,
        const float* __restrict__ biasZ,
        float* __restrict__ out,                 // [M_][512] fp32
        u64* __restrict__ Hpub,                  // [8][128][128]
        uint32_t* __restrict__ counter) {
    // K-loop: A substage s at smem + s*4096 shorts (8 KB each).
    // Epilogue reuse: seg = float2[32][128] at [0,32KB); hinL at [32KB,48KB)
    __shared__ unsigned short smem[24576];       // 48 KB
    __shared__ uint32_t vid_s;

    const int tid = threadIdx.x;
    if (tid == 0) vid_s = atomicAdd(counter, 1u);
    __syncthreads();
    const int vid   = (int)vid_s;
    const int low3  = vid & 7;
    const int ni    = (vid >> 3) & 3;
    const int rem   = vid >> 5;                  // 0..31
    const int pos   = rem >> 2;                  // 0..7  t-chunk
    const int b     = ((rem & 3) << 3) | low3;   // 0..31
    const int chain = ni * 32 + b;               // 0..127
    const int h0    = ni * 128;
    const int browBase = b * TP_ + pos * 128;    // Ab2 row of tile t=0, tap0

    const int lane = tid & 63;
    const int wave = tid >> 6;
    const int wm   = wave >> 1, wn = wave & 1;
    const int lm   = lane & 15, quad = lane >> 4;

    // A staging chunk ids (512 chunks/substage; wave covers 128: lane, lane+64)
    const int c0 = wave * 128 + lane;
    const int c1 = c0 + 64;
    const int r0 = c0 >> 2, q0 = (c0 & 3) ^ ((r0 >> 2) & 3);
    const int r1 = c1 >> 2, q1 = (c1 & 3) ^ ((r1 >> 2) & 3);

    const unsigned short* pA0 = Ab2 + (size_t)(browBase + r0) * 512 + q0 * 8;
    const unsigned short* pA1 = Ab2 + (size_t)(browBase + r1) * 512 + q1 * 8;

    unsigned short* dA0 = smem + wave * 1024;    // + s*4096
    unsigned short* dA1 = smem + wave * 1024 + 512;

    // B fragment base: frag(gate,ksub,c) = wq + gate*524288 + ksub*4096 + c*512
    const unsigned short* wq = Wq + ni * 131072 + wn * 2048 + lane * 8;

    int offA[4];
    #pragma unroll
    for (int r = 0; r < 4; ++r) {
        int ml = wm * 64 + r * 16 + lm;
        offA[r] = (4 * ml + (quad ^ ((ml >> 2) & 3))) * 8;
    }

    floatx4 accF[4][4] = {};
    floatx4 accZ[4][4] = {};

    for (int kt2 = 0; kt2 < 16; ++kt2) {
        const int tap = kt2 >> 3;
        const int i0  = (kt2 & 7) * 64;
        #pragma unroll
        for (int s = 0; s < 2; ++s) {
            const int aoff = tap * 512 + i0 + s * 32;
            GLL(pA0 + aoff, dA0 + s * 4096);
            GLL(pA1 + aoff, dA1 + s * 4096);
        }
        __syncthreads();

        #pragma unroll
        for (int s = 0; s < 2; ++s) {
            const int ksub = kt2 * 2 + s;
            const unsigned short* wqk = wq + ksub * 4096;
            bf16x8 af[4], bF[4], bZ[4];
            #pragma unroll
            for (int c = 0; c < 4; ++c) {
                bF[c] = *(const bf16x8*)(wqk + c * 512);
                bZ[c] = *(const bf16x8*)(wqk + 524288 + c * 512);
            }
            #pragma unroll
            for (int r = 0; r < 4; ++r) af[r] = *(const bf16x8*)(smem + s * 4096 + offA[r]);
            #pragma unroll
            for (int r = 0; r < 4; ++r) {
                #pragma unroll
                for (int c = 0; c < 4; ++c) {
                    accF[r][c] = __builtin_amdgcn_mfma_f32_16x16x32_bf16(
                                    af[r], bF[c], accF[r][c], 0, 0, 0);
                    accZ[r][c] = __builtin_amdgcn_mfma_f32_16x16x32_bf16(
                                    af[r], bZ[c], accZ[r][c], 0, 0, 0);
                }
            }
        }
        __syncthreads();
    }

    // ================= epilogue: sigmoid + segment affines =================
    float bfv[4], bzv[4];
    #pragma unroll
    for (int c = 0; c < 4; ++c) {
        int hc = h0 + wn * 64 + c * 16 + lm;
        bfv[c] = biasF[hc];
        bzv[c] = biasZ[hc];
    }

    float2* seg  = (float2*)smem;                // [32][128] 32 KB
    float*  hinL = (float*)&smem[16384];         // [32][128] 16 KB

    #pragma unroll
    for (int r = 0; r < 4; ++r) {
        const int sid = wm * 16 + r * 4 + quad;  // segment of 4 t's
        #pragma unroll
        for (int c = 0; c < 4; ++c) {
            float A = 1.f, C = 0.f;
            #pragma unroll
            for (int v = 0; v < 4; ++v) {
                float f = sigm(accF[r][c][v] + bfv[c]);
                float z = sigm(accZ[r][c][v] + bzv[c]);
                accF[r][c][v] = f;               // keep f
                accZ[r][c][v] = z;               // keep z
                A *= f;
                C = fmaf(f, C - z, z);
            }
            seg[sid * 128 + wn * 64 + c * 16 + lm] = make_float2(A, C);
        }
    }
    __syncthreads();

    // per-h block affine (threads 0..127), lookback, publish, local states
    float Hin = 0.f;
    if (tid < 128) {
        float At = 1.f, Ct = 0.f;
        #pragma unroll 8
        for (int s = 0; s < 32; ++s) {
            float2 sc = seg[s * 128 + tid];
            Ct = fmaf(sc.x, Ct, sc.y);
            At *= sc.x;
        }
        if (pos > 0) {
            u64* p = &Hpub[((size_t)(pos - 1) * 128 + chain) * 128 + tid];
            u64 v;
            while (((v = atomicAdd(p, 0ull)) >> 32) == 0ull)
                __builtin_amdgcn_s_sleep(2);
            Hin = __uint_as_float((uint32_t)v);
        }
        if (pos < 7) {
            float Hout = fmaf(At, Hin, Ct);
            u64 pv = 0x100000000ull | (u64)__float_as_uint(Hout);
            atomicExch(&Hpub[((size_t)pos * 128 + chain) * 128 + tid], pv);
        }
        // per-segment entry states
        float run = Hin;
        #pragma unroll 8
        for (int s = 0; s < 32; ++s) {
            hinL[s * 128 + tid] = run;
            float2 sc = seg[s * 128 + tid];
            run = fmaf(sc.x, run, sc.y);
        }
    }
    __syncthreads();

    // replay tile from registers, write output
    const int rowBase = b * T_ + pos * 128;
    #pragma unroll
    for (int r = 0; r < 4; ++r) {
        const int sid = wm * 16 + r * 4 + quad;
        #pragma unroll
        for (int c = 0; c < 4; ++c) {
            const int hc = h0 + wn * 64 + c * 16 + lm;
            float hs = hinL[sid * 128 + (hc - h0)];
            #pragma unroll
            for (int v = 0; v < 4; ++v) {
                float f = accF[r][c][v];
                float z = accZ[r][c][v];
                hs = fmaf(f, hs - z, z);
                const size_t row = (size_t)(rowBase + wm * 64 + r * 16 + quad * 4 + v);
                out[row * H_ + hc] = hs;
            }
        }
    }
}

// ---------------------------------------------------------------------------
extern "C" void kernel_launch(void* const* d_in, const int* in_sizes, int n_in,
                              void* d_out, int out_size, void* d_ws, size_t ws_size,
                              hipStream_t stream) {
    const float* x  = (const float*)d_in[0];
    const float* Wz = (const float*)d_in[2];
    const float* bz = (const float*)d_in[3];
    const float* Wf = (const float*)d_in[4];
    const float* bf = (const float*)d_in[5];
    float* out = (float*)d_out;

    char* ws = (char*)d_ws;
    unsigned short* Ab2  = (unsigned short*)(ws);                            // 33.6 MB
    unsigned short* Wq   = (unsigned short*)(ws + (size_t)34 * 1024 * 1024); // 2 MB
    u64*            Hpub = (u64*)(ws + (size_t)36 * 1024 * 1024);            // 1 MB
    uint32_t*       cnt  = (uint32_t*)(ws + (size_t)37 * 1024 * 1024);

    prep<<<NB_BUILD + NB_PACK + NB_ZERO, 256, 0, stream>>>(
        x, Wf, Wz, Ab2, Wq, (uint4*)Hpub, cnt);

    mfma_gemm_scan<<<1024, 256, 0, stream>>>(Ab2, Wq, bf, bz, out, Hpub, cnt);
}